// Round 3
// baseline (424.738 us; speedup 1.0000x reference)
//
#include <hip/hip_runtime.h>
#include <stdint.h>

typedef short bf16x8 __attribute__((ext_vector_type(8)));
typedef float f32x4 __attribute__((ext_vector_type(4)));

#define M_ROWS 8192
#define N_OUT  4096
#define K_DIM  4096
#define NW     16777216.0   // number of weights

// ---------------- async global->LDS (16B per lane) ----------------
__device__ __forceinline__ void gload16(const void* g, void* l) {
    __builtin_amdgcn_global_load_lds((const __attribute__((address_space(1))) void*)g,
                                     (__attribute__((address_space(3))) void*)l,
                                     16, 0, 0);
}

// RNE f32 -> bf16 bits
__device__ __forceinline__ unsigned short f2bf(float f) {
    unsigned u = __float_as_uint(f);
    unsigned r = 0x7FFFu + ((u >> 16) & 1u);
    return (unsigned short)((u + r) >> 16);
}

// ---------------- gamma = sum |w| (double accumulation) ----------------
__global__ __launch_bounds__(256) void k_gamma(const float* __restrict__ w,
                                               double* __restrict__ sum) {
    const int n4 = (K_DIM * N_OUT) / 4;
    int idx = blockIdx.x * blockDim.x + threadIdx.x;
    int stride = gridDim.x * blockDim.x;
    const float4* w4 = (const float4*)w;
    double local = 0.0;
    for (int i = idx; i < n4; i += stride) {
        float4 v = w4[i];
        local += (double)fabsf(v.x) + (double)fabsf(v.y) +
                 (double)fabsf(v.z) + (double)fabsf(v.w);
    }
    __shared__ double sm[256];
    sm[threadIdx.x] = local;
    __syncthreads();
    for (int s = 128; s > 0; s >>= 1) {
        if (threadIdx.x < s) sm[threadIdx.x] += sm[threadIdx.x + s];
        __syncthreads();
    }
    if (threadIdx.x == 0) atomicAdd(sum, sm[0]);
}

// ---------------- quantize W -> ternary bf16 + bin counts ----------------
__global__ __launch_bounds__(256) void k_quant(const float* __restrict__ w,
                                               const double* __restrict__ sum,
                                               unsigned short* __restrict__ wq,
                                               unsigned int* __restrict__ counts,
                                               int do_store) {
    const float gamma = (float)(*sum / NW);
    const float denom = gamma + 1e-8f;
    const int n4 = (K_DIM * N_OUT) / 4;
    int idx = blockIdx.x * blockDim.x + threadIdx.x;
    int stride = gridDim.x * blockDim.x;
    const float4* w4 = (const float4*)w;
    unsigned cm = 0, cp = 0;
    for (int i = idx; i < n4; i += stride) {
        float4 v = w4[i];
        float q0 = fminf(1.f, fmaxf(-1.f, rintf(v.x / denom)));
        float q1 = fminf(1.f, fmaxf(-1.f, rintf(v.y / denom)));
        float q2 = fminf(1.f, fmaxf(-1.f, rintf(v.z / denom)));
        float q3 = fminf(1.f, fmaxf(-1.f, rintf(v.w / denom)));
        cm += (q0 < -0.5f) + (q1 < -0.5f) + (q2 < -0.5f) + (q3 < -0.5f);
        cp += (q0 >  0.5f) + (q1 >  0.5f) + (q2 >  0.5f) + (q3 >  0.5f);
        if (do_store) {
            unsigned b0 = (q0 < -0.5f) ? 0xBF80u : (q0 > 0.5f ? 0x3F80u : 0u);
            unsigned b1 = (q1 < -0.5f) ? 0xBF80u : (q1 > 0.5f ? 0x3F80u : 0u);
            unsigned b2 = (q2 < -0.5f) ? 0xBF80u : (q2 > 0.5f ? 0x3F80u : 0u);
            unsigned b3 = (q3 < -0.5f) ? 0xBF80u : (q3 > 0.5f ? 0x3F80u : 0u);
            uint2 pk;
            pk.x = b0 | (b1 << 16);
            pk.y = b2 | (b3 << 16);
            ((uint2*)wq)[i] = pk;
        }
    }
    __shared__ unsigned smc[512];
    smc[threadIdx.x] = cm;
    smc[256 + threadIdx.x] = cp;
    __syncthreads();
    for (int s = 128; s > 0; s >>= 1) {
        if (threadIdx.x < s) {
            smc[threadIdx.x] += smc[threadIdx.x + s];
            smc[256 + threadIdx.x] += smc[256 + threadIdx.x + s];
        }
        __syncthreads();
    }
    if (threadIdx.x == 0) {
        atomicAdd(&counts[0], smc[0]);
        atomicAdd(&counts[1], smc[256]);
    }
}

// ---------------- x f32 -> bf16 ----------------
__global__ __launch_bounds__(256) void k_cvt(const float* __restrict__ x,
                                             unsigned short* __restrict__ xb) {
    const int n4 = (M_ROWS * K_DIM) / 4;
    int idx = blockIdx.x * blockDim.x + threadIdx.x;
    int stride = gridDim.x * blockDim.x;
    const float4* x4 = (const float4*)x;
    for (int i = idx; i < n4; i += stride) {
        float4 v = x4[i];
        uint2 pk;
        pk.x = (unsigned)f2bf(v.x) | ((unsigned)f2bf(v.y) << 16);
        pk.y = (unsigned)f2bf(v.z) | ((unsigned)f2bf(v.w) << 16);
        ((uint2*)xb)[i] = pk;
    }
}

// ---------------- entropy + t_current ----------------
__global__ void k_fin(const unsigned int* __restrict__ counts,
                      float* __restrict__ outs) {
    double n = NW;
    double c1 = (double)counts[0];
    double c2 = (double)counts[1];
    double c0 = n - c1 - c2;
    double H = 0.0;
    if (c1 > 0.0) { double p = c1 / n; H -= p * log2(p); }
    if (c0 > 0.0) { double p = c0 / n; H -= p * log2(p); }
    if (c2 > 0.0) { double p = c2 / n; H -= p * log2(p); }
    float Hf = (float)H;
    float heat = 100.0f * fmaxf(Hf, 0.0f);
    outs[0] = -10.0f + (50.0f + heat) * 0.5f;
    outs[1] = Hf;
}

// ================= 256x256 8-phase bf16 MFMA GEMM =================
// C[M,N] = A[M,K] * B[N,K]^T, A,B bf16, C f32.
// 512 threads = 8 waves (2 M-waves x 4 N-waves); per-wave output 128x64.
// LDS 128KB: buf[2] x { A-half[2] 16KB, B-half[2] 16KB }.
// Half-tile = 128 rows x 64 cols bf16 (128 B/row), staged 1 per phase.
//
// Bank-conflict swizzle (bit-6 x row-parity involution):
//   LDS(row, b) holds G(row, b ^ ((row&1)<<6)).
//   Write side: global_load_lds dest stays LINEAR; the global SOURCE col is
//   pre-swizzled:  scol_bf16 = (slot*8) ^ ((row&1)*32).
//   Read side: byte-in-row = ((ks*64) ^ ((fr&1)<<6)) + khi*16.
//   => for any fragment read, even-fr lanes occupy banks [ks*16,+16) and
//   odd-fr lanes the other 16 banks: 8 words/bank = b128 floor, 0 conflicts.

__device__ __forceinline__ void stage_half(const unsigned short* __restrict__ A,
                                           const unsigned short* __restrict__ B,
                                           char* lds, int H, int tm, int tn,
                                           int tid, int scol) {
    const int kt = H >> 2;
    const int q  = H & 3;
    const unsigned short* src = (q & 2) ? B : A;
    int rb = ((q & 2) ? tn : tm) * 256 + (q & 1) * 128;
    const unsigned short* g0 = src + (size_t)(rb + (tid >> 3)) * K_DIM + kt * 64 + scol;
    char* d = lds + ((size_t)(kt & 1) << 16) + ((q & 2) << 14) + ((q & 1) << 14) + tid * 16;
    gload16(g0, d);
    gload16(g0 + (size_t)64 * K_DIM, d + 8192);   // +64 rows: parity preserved
}

#define MFMA_QUAD(ACCM, ACCN, AF, BF)                                          \
    __builtin_amdgcn_s_barrier();                                              \
    asm volatile("s_waitcnt lgkmcnt(0)" ::: "memory");                         \
    __builtin_amdgcn_s_setprio(1);                                             \
    _Pragma("unroll") for (int mm = 0; mm < 4; ++mm)                           \
    _Pragma("unroll") for (int nn = 0; nn < 2; ++nn)                           \
    _Pragma("unroll") for (int ks = 0; ks < 2; ++ks)                           \
        acc[(ACCM) + mm][(ACCN) + nn] = __builtin_amdgcn_mfma_f32_16x16x32_bf16( \
            AF[mm][ks], BF[nn][ks], acc[(ACCM) + mm][(ACCN) + nn], 0, 0, 0);   \
    __builtin_amdgcn_s_setprio(0);

__global__ __launch_bounds__(512, 2) void k_gemm2(const unsigned short* __restrict__ A,
                                                  const unsigned short* __restrict__ B,
                                                  float* __restrict__ C) {
    extern __shared__ char smem[];
    const int tid  = threadIdx.x;
    const int lane = tid & 63;
    const int wid  = tid >> 6;
    const int wr   = wid >> 2;        // 0..1  (M)
    const int wc   = wid & 3;         // 0..3  (N)
    const int fr   = lane & 15;
    const int khi  = lane >> 4;       // 0..3

    // XCD-aware swizzle (nwg=512, divisible by 8 -> bijective simple form).
    // Each XCD gets 2 B-panel columns (4MB bf16 = its L2) x all 32 row-tiles.
    const int lin = blockIdx.x;
    const int s   = (lin & 7) * 64 + (lin >> 3);
    const int tm  = s & 31;           // 0..31 (M tiles)
    const int tn  = s >> 5;           // 0..15 (N tiles)

    // staging source col (inverse of the bit6^rowparity swizzle)
    const int scol = ((tid & 7) * 8) ^ (((tid >> 3) & 1) << 5);
    // read-side: rx flips the 64B half by row parity (all frag rows have parity fr&1)
    const int rx = (fr & 1) << 6;

    f32x4 acc[8][4] = {};

    // prologue: stage K-tile 0 fully + A0 of K-tile 1; counted wait
    for (int H = 0; H < 5; ++H) stage_half(A, B, smem, H, tm, tn, tid, scol);
    asm volatile("s_waitcnt vmcnt(2)" ::: "memory");
    __builtin_amdgcn_s_barrier();

    bf16x8 afr[4][2], b0[2][2], b1[2][2];

    for (int tau = 0; tau < 64; ++tau) {
        char* abase = smem + ((size_t)(tau & 1) << 16) + ((size_t)wr << 14);
        char* bbase = smem + ((size_t)(tau & 1) << 16) + 32768 + ((size_t)(wc >> 1) << 14);
        const int brow0 = (wc & 1) * 64;
        const int g = tau * 4;

        // ---- phase 0: read A[qm0] (8) + B[qn0] (4); stage; MFMA quad (0,0)
#pragma unroll
        for (int mm = 0; mm < 4; ++mm)
#pragma unroll
            for (int ks = 0; ks < 2; ++ks)
                afr[mm][ks] = *(const bf16x8*)(abase + ((mm * 16 + fr) * 128 + ((ks * 64) ^ rx) + khi * 16));
#pragma unroll
        for (int nn = 0; nn < 2; ++nn)
#pragma unroll
            for (int ks = 0; ks < 2; ++ks)
                b0[nn][ks] = *(const bf16x8*)(bbase + ((brow0 + nn * 16 + fr) * 128 + ((ks * 64) ^ rx) + khi * 16));
        if (g + 5 < 256) stage_half(A, B, smem, g + 5, tm, tn, tid, scol);
        MFMA_QUAD(0, 0, afr, b0)
        __builtin_amdgcn_s_barrier();

        // ---- phase 1: read B[qn1] (4); stage; MFMA quad (0,1)
#pragma unroll
        for (int nn = 0; nn < 2; ++nn)
#pragma unroll
            for (int ks = 0; ks < 2; ++ks)
                b1[nn][ks] = *(const bf16x8*)(bbase + ((brow0 + 32 + nn * 16 + fr) * 128 + ((ks * 64) ^ rx) + khi * 16));
        if (g + 6 < 256) stage_half(A, B, smem, g + 6, tm, tn, tid, scol);
        MFMA_QUAD(0, 2, afr, b1)
        __builtin_amdgcn_s_barrier();

        // ---- phase 2: read A[qm1] (8); stage; MFMA quad (1,1)
#pragma unroll
        for (int mm = 0; mm < 4; ++mm)
#pragma unroll
            for (int ks = 0; ks < 2; ++ks)
                afr[mm][ks] = *(const bf16x8*)(abase + ((64 + mm * 16 + fr) * 128 + ((ks * 64) ^ rx) + khi * 16));
        if (g + 7 < 256) stage_half(A, B, smem, g + 7, tm, tn, tid, scol);
        MFMA_QUAD(4, 2, afr, b1)
        __builtin_amdgcn_s_barrier();

        // ---- phase 3: no reads (b0 still live); stage into just-freed buffer;
        //      MFMA quad (1,0); counted vmcnt at the K-tile boundary
        if (g + 8 < 256) stage_half(A, B, smem, g + 8, tm, tn, tid, scol);
        MFMA_QUAD(4, 0, afr, b0)
        if (tau < 62) {
            asm volatile("s_waitcnt vmcnt(2)" ::: "memory");
        } else {
            asm volatile("s_waitcnt vmcnt(0)" ::: "memory");
        }
        __builtin_amdgcn_s_barrier();
    }

    // epilogue: C/D layout col = lane&15, row = khi*4 + j
    const size_t crow = (size_t)(tm * 256 + wr * 128 + khi * 4);
    const int    ccol = tn * 256 + wc * 64 + fr;
#pragma unroll
    for (int m = 0; m < 8; ++m)
#pragma unroll
        for (int n = 0; n < 4; ++n) {
            float* cp = C + (crow + m * 16) * N_OUT + (ccol + n * 16);
#pragma unroll
            for (int j = 0; j < 4; ++j)
                cp[(size_t)j * N_OUT] = acc[m][n][j];
        }
}

// ---------------- fallback fp32 GEMM (only if ws too small) ----------------
__global__ __launch_bounds__(256) void fb_gemm(const float* __restrict__ X,
                                               const float* __restrict__ W,
                                               const double* __restrict__ sum,
                                               float* __restrict__ C) {
    __shared__ float Xs[64][33];
    __shared__ float Ws[64][33];
    const float gamma = (float)(*sum / NW);
    const float denom = gamma + 1e-8f;
    const int tid = threadIdx.x;
    const int bm = blockIdx.y * 64;
    const int bn = blockIdx.x * 64;
    const int tr = tid >> 4, tc = tid & 15;
    const int lrow = tid >> 2;
    const int lcol = (tid & 3) * 8;
    float acc[4][4] = {};
    for (int k0 = 0; k0 < K_DIM; k0 += 32) {
        const float4* xs = (const float4*)(X + (size_t)(bm + lrow) * K_DIM + k0 + lcol);
        float4 v0 = xs[0], v1 = xs[1];
        Xs[lrow][lcol + 0] = v0.x; Xs[lrow][lcol + 1] = v0.y;
        Xs[lrow][lcol + 2] = v0.z; Xs[lrow][lcol + 3] = v0.w;
        Xs[lrow][lcol + 4] = v1.x; Xs[lrow][lcol + 5] = v1.y;
        Xs[lrow][lcol + 6] = v1.z; Xs[lrow][lcol + 7] = v1.w;
        const float4* wsrc = (const float4*)(W + (size_t)(bn + lrow) * K_DIM + k0 + lcol);
        float4 w0 = wsrc[0], w1 = wsrc[1];
        Ws[lrow][lcol + 0] = fminf(1.f, fmaxf(-1.f, rintf(w0.x / denom)));
        Ws[lrow][lcol + 1] = fminf(1.f, fmaxf(-1.f, rintf(w0.y / denom)));
        Ws[lrow][lcol + 2] = fminf(1.f, fmaxf(-1.f, rintf(w0.z / denom)));
        Ws[lrow][lcol + 3] = fminf(1.f, fmaxf(-1.f, rintf(w0.w / denom)));
        Ws[lrow][lcol + 4] = fminf(1.f, fmaxf(-1.f, rintf(w1.x / denom)));
        Ws[lrow][lcol + 5] = fminf(1.f, fmaxf(-1.f, rintf(w1.y / denom)));
        Ws[lrow][lcol + 6] = fminf(1.f, fmaxf(-1.f, rintf(w1.z / denom)));
        Ws[lrow][lcol + 7] = fminf(1.f, fmaxf(-1.f, rintf(w1.w / denom)));
        __syncthreads();
#pragma unroll 8
        for (int kk = 0; kk < 32; ++kk) {
            float a0 = Xs[tr * 4 + 0][kk], a1 = Xs[tr * 4 + 1][kk];
            float a2 = Xs[tr * 4 + 2][kk], a3 = Xs[tr * 4 + 3][kk];
            float b0 = Ws[tc * 4 + 0][kk], b1 = Ws[tc * 4 + 1][kk];
            float b2 = Ws[tc * 4 + 2][kk], b3 = Ws[tc * 4 + 3][kk];
            acc[0][0] += a0 * b0; acc[0][1] += a0 * b1; acc[0][2] += a0 * b2; acc[0][3] += a0 * b3;
            acc[1][0] += a1 * b0; acc[1][1] += a1 * b1; acc[1][2] += a1 * b2; acc[1][3] += a1 * b3;
            acc[2][0] += a2 * b0; acc[2][1] += a2 * b1; acc[2][2] += a2 * b2; acc[2][3] += a2 * b3;
            acc[3][0] += a3 * b0; acc[3][1] += a3 * b1; acc[3][2] += a3 * b2; acc[3][3] += a3 * b3;
        }
        __syncthreads();
    }
#pragma unroll
    for (int i = 0; i < 4; ++i)
#pragma unroll
        for (int j = 0; j < 4; ++j)
            C[(size_t)(bm + tr * 4 + i) * N_OUT + (bn + tc * 4 + j)] = acc[i][j];
}

extern "C" void kernel_launch(void* const* d_in, const int* in_sizes, int n_in,
                              void* d_out, int out_size, void* d_ws, size_t ws_size,
                              hipStream_t stream) {
    (void)in_sizes; (void)n_in; (void)out_size;
    const float* x = (const float*)d_in[0];
    const float* w = (const float*)d_in[1];
    float* out = (float*)d_out;
    float* scalars = out + (size_t)M_ROWS * N_OUT;   // [t_current, entropy]

    double* sum = (double*)d_ws;
    unsigned int* counts = (unsigned int*)((char*)d_ws + 8);
    unsigned short* xb = (unsigned short*)((char*)d_ws + 64);
    unsigned short* wq = (unsigned short*)((char*)d_ws + 64 + (size_t)M_ROWS * K_DIM * 2);

    const size_t need = 64 + (size_t)M_ROWS * K_DIM * 2 + (size_t)N_OUT * K_DIM * 2;
    const int fast = (ws_size >= need);

    hipMemsetAsync(d_ws, 0, 16, stream);
    k_gamma<<<1024, 256, 0, stream>>>(w, sum);

    if (fast) {
        k_cvt<<<2048, 256, 0, stream>>>(x, xb);
        k_quant<<<1024, 256, 0, stream>>>(w, sum, wq, counts, 1);
        k_fin<<<1, 1, 0, stream>>>(counts, scalars);
        hipFuncSetAttribute(reinterpret_cast<const void*>(k_gemm2),
                            hipFuncAttributeMaxDynamicSharedMemorySize, 131072);
        k_gemm2<<<dim3(512), 512, 131072, stream>>>(xb, wq, out);
    } else {
        k_quant<<<1024, 256, 0, stream>>>(w, sum, nullptr, counts, 0);
        k_fin<<<1, 1, 0, stream>>>(counts, scalars);
        dim3 grid(N_OUT / 64, M_ROWS / 64);
        fb_gemm<<<grid, 256, 0, stream>>>(x, w, sum, out);
    }
}

// Round 5
// 370.360 us; speedup vs baseline: 1.1468x; 1.1468x over previous
//
#include <hip/hip_runtime.h>
#include <stdint.h>

typedef short bf16x8 __attribute__((ext_vector_type(8)));
typedef float f32x4 __attribute__((ext_vector_type(4)));

#define M_ROWS 8192
#define N_OUT  4096
#define K_DIM  4096
#define NW     16777216.0   // number of weights

// ---------------- async global->LDS (16B per lane) ----------------
__device__ __forceinline__ void gload16(const void* g, void* l) {
    __builtin_amdgcn_global_load_lds((const __attribute__((address_space(1))) void*)g,
                                     (__attribute__((address_space(3))) void*)l,
                                     16, 0, 0);
}

// RNE f32 -> bf16 bits
__device__ __forceinline__ unsigned short f2bf(float f) {
    unsigned u = __float_as_uint(f);
    unsigned r = 0x7FFFu + ((u >> 16) & 1u);
    return (unsigned short)((u + r) >> 16);
}

// ---------------- gamma = sum |w| (double accumulation) ----------------
__global__ __launch_bounds__(256) void k_gamma(const float* __restrict__ w,
                                               double* __restrict__ sum) {
    const int n4 = (K_DIM * N_OUT) / 4;
    int idx = blockIdx.x * blockDim.x + threadIdx.x;
    int stride = gridDim.x * blockDim.x;
    const float4* w4 = (const float4*)w;
    double local = 0.0;
    for (int i = idx; i < n4; i += stride) {
        float4 v = w4[i];
        local += (double)fabsf(v.x) + (double)fabsf(v.y) +
                 (double)fabsf(v.z) + (double)fabsf(v.w);
    }
    __shared__ double sm[256];
    sm[threadIdx.x] = local;
    __syncthreads();
    for (int s = 128; s > 0; s >>= 1) {
        if (threadIdx.x < s) sm[threadIdx.x] += sm[threadIdx.x + s];
        __syncthreads();
    }
    if (threadIdx.x == 0) atomicAdd(sum, sm[0]);
}

// ---------------- quantize W -> ternary bf16 + bin counts ----------------
__global__ __launch_bounds__(256) void k_quant(const float* __restrict__ w,
                                               const double* __restrict__ sum,
                                               unsigned short* __restrict__ wq,
                                               unsigned int* __restrict__ counts,
                                               int do_store) {
    const float gamma = (float)(*sum / NW);
    const float denom = gamma + 1e-8f;
    const int n4 = (K_DIM * N_OUT) / 4;
    int idx = blockIdx.x * blockDim.x + threadIdx.x;
    int stride = gridDim.x * blockDim.x;
    const float4* w4 = (const float4*)w;
    unsigned cm = 0, cp = 0;
    for (int i = idx; i < n4; i += stride) {
        float4 v = w4[i];
        float q0 = fminf(1.f, fmaxf(-1.f, rintf(v.x / denom)));
        float q1 = fminf(1.f, fmaxf(-1.f, rintf(v.y / denom)));
        float q2 = fminf(1.f, fmaxf(-1.f, rintf(v.z / denom)));
        float q3 = fminf(1.f, fmaxf(-1.f, rintf(v.w / denom)));
        cm += (q0 < -0.5f) + (q1 < -0.5f) + (q2 < -0.5f) + (q3 < -0.5f);
        cp += (q0 >  0.5f) + (q1 >  0.5f) + (q2 >  0.5f) + (q3 >  0.5f);
        if (do_store) {
            unsigned b0 = (q0 < -0.5f) ? 0xBF80u : (q0 > 0.5f ? 0x3F80u : 0u);
            unsigned b1 = (q1 < -0.5f) ? 0xBF80u : (q1 > 0.5f ? 0x3F80u : 0u);
            unsigned b2 = (q2 < -0.5f) ? 0xBF80u : (q2 > 0.5f ? 0x3F80u : 0u);
            unsigned b3 = (q3 < -0.5f) ? 0xBF80u : (q3 > 0.5f ? 0x3F80u : 0u);
            uint2 pk;
            pk.x = b0 | (b1 << 16);
            pk.y = b2 | (b3 << 16);
            ((uint2*)wq)[i] = pk;
        }
    }
    __shared__ unsigned smc[512];
    smc[threadIdx.x] = cm;
    smc[256 + threadIdx.x] = cp;
    __syncthreads();
    for (int s = 128; s > 0; s >>= 1) {
        if (threadIdx.x < s) {
            smc[threadIdx.x] += smc[threadIdx.x + s];
            smc[256 + threadIdx.x] += smc[256 + threadIdx.x + s];
        }
        __syncthreads();
    }
    if (threadIdx.x == 0) {
        atomicAdd(&counts[0], smc[0]);
        atomicAdd(&counts[1], smc[256]);
    }
}

// ---------------- x f32 -> bf16 ----------------
__global__ __launch_bounds__(256) void k_cvt(const float* __restrict__ x,
                                             unsigned short* __restrict__ xb) {
    const int n4 = (M_ROWS * K_DIM) / 4;
    int idx = blockIdx.x * blockDim.x + threadIdx.x;
    int stride = gridDim.x * blockDim.x;
    const float4* x4 = (const float4*)x;
    for (int i = idx; i < n4; i += stride) {
        float4 v = x4[i];
        uint2 pk;
        pk.x = (unsigned)f2bf(v.x) | ((unsigned)f2bf(v.y) << 16);
        pk.y = (unsigned)f2bf(v.z) | ((unsigned)f2bf(v.w) << 16);
        ((uint2*)xb)[i] = pk;
    }
}

// ---------------- entropy + t_current ----------------
__global__ void k_fin(const unsigned int* __restrict__ counts,
                      float* __restrict__ outs) {
    double n = NW;
    double c1 = (double)counts[0];
    double c2 = (double)counts[1];
    double c0 = n - c1 - c2;
    double H = 0.0;
    if (c1 > 0.0) { double p = c1 / n; H -= p * log2(p); }
    if (c0 > 0.0) { double p = c0 / n; H -= p * log2(p); }
    if (c2 > 0.0) { double p = c2 / n; H -= p * log2(p); }
    float Hf = (float)H;
    float heat = 100.0f * fmaxf(Hf, 0.0f);
    outs[0] = -10.0f + (50.0f + heat) * 0.5f;
    outs[1] = Hf;
}

// ================= 256x256 8-phase bf16 MFMA GEMM =================
// C[M,N] = A[M,K] * B[N,K]^T, A,B bf16, C f32.
// 512 threads = 8 waves (2 M x 4 N); per-wave output 128x64.
// LDS 128KB: buf[2] x { A0,A1,B0,B1 halves, 16KB each }.
//
// FRAGMENT-MAJOR LDS LAYOUT (zero bank conflicts by construction):
//   Each half (128 rows x 64 cols bf16) is stored as 16 fragments of 1KB:
//     off = (ks*8 + sub16)*1024 + lane*16
//   holding global (row = sub16*16 + (lane&15), cols = kt*64 + ks*32 + (lane>>4)*8 .. +8).
//   Every ds_read_b128 is base + lane*16 + IMMEDIATE -> contiguous, conflict-free.
//   global_load_lds dest stays linear (tid*16); permutation is in the per-lane
//   GLOBAL source address (row (tid>>6)*16+(tid&15), col (tid>>4&3)*8; 2nd gload +32).
//
// PIPELINE (schedule Y): during tau stage A0(t+1)@ph0, A1(t+1)@ph1,
//   B0(t+2)@ph2, B1(t+2)@ph3 (B slots free after ph1, A slots after ph2).
//   ONE gate per tau at ph3: vmcnt(4) -> all 4 halves of t+1 landed (correct
//   for every wave; every wave reads all halves at ph0), 2 B-stages in flight.

__device__ __forceinline__ void stage_half(const unsigned short* __restrict__ A,
                                           const unsigned short* __restrict__ B,
                                           char* lds, int H, int tm, int tn,
                                           int tid) {
    const int kt = H >> 2;
    const int q  = H & 3;                      // 0=A0 1=A1 2=B0 3=B1
    const unsigned short* src = (q & 2) ? B : A;
    const int rb = ((q & 2) ? tn : tm) * 256 + (q & 1) * 128;
    const int row = rb + ((tid >> 6) << 4) + (tid & 15);
    const unsigned short* g0 = src + (size_t)row * K_DIM + kt * 64 + ((tid >> 4) & 3) * 8;
    char* d = lds + ((size_t)(kt & 1) << 16) + (q << 14) + tid * 16;
    gload16(g0, d);              // ks=0: cols [khi*8, +8)
    gload16(g0 + 32, d + 8192);  // ks=1: cols [32+khi*8, +8)
}

#define MFMA_QUAD(ACCM, ACCN, AF, BF)                                          \
    __builtin_amdgcn_s_barrier();                                              \
    asm volatile("s_waitcnt lgkmcnt(0)" ::: "memory");                         \
    __builtin_amdgcn_s_setprio(1);                                             \
    _Pragma("unroll") for (int mm = 0; mm < 4; ++mm)                           \
    _Pragma("unroll") for (int nn = 0; nn < 2; ++nn)                           \
    _Pragma("unroll") for (int ks = 0; ks < 2; ++ks)                           \
        acc[(ACCM) + mm][(ACCN) + nn] = __builtin_amdgcn_mfma_f32_16x16x32_bf16( \
            AF[mm][ks], BF[nn][ks], acc[(ACCM) + mm][(ACCN) + nn], 0, 0, 0);   \
    __builtin_amdgcn_s_setprio(0);

__global__ __launch_bounds__(512, 2) void k_gemm2(const unsigned short* __restrict__ A,
                                                  const unsigned short* __restrict__ B,
                                                  float* __restrict__ C) {
    extern __shared__ char smem[];
    const int tid  = threadIdx.x;
    const int lane = tid & 63;
    const int wid  = tid >> 6;
    const int wr   = wid >> 2;        // 0..1  (M)
    const int wc   = wid & 3;         // 0..3  (N)
    const int fr   = lane & 15;
    const int khi  = lane >> 4;       // 0..3

    // XCD-aware swizzle (nwg=512 divisible by 8 -> bijective simple form).
    const int lin = blockIdx.x;
    const int s   = (lin & 7) * 64 + (lin >> 3);
    const int tm  = s & 31;           // 0..31 (M tiles)
    const int tn  = s >> 5;           // 0..15 (N tiles)

    f32x4 acc[8][4] = {};

    // prologue: tile0 all halves + B0,B1 of tile1; full drain once
    stage_half(A, B, smem, 0, tm, tn, tid);
    stage_half(A, B, smem, 1, tm, tn, tid);
    stage_half(A, B, smem, 2, tm, tn, tid);
    stage_half(A, B, smem, 3, tm, tn, tid);
    stage_half(A, B, smem, 6, tm, tn, tid);
    stage_half(A, B, smem, 7, tm, tn, tid);
    asm volatile("s_waitcnt vmcnt(0)" ::: "memory");
    __builtin_amdgcn_s_barrier();

    bf16x8 afr[4][2], b0[2][2], b1[2][2];
    const int bsel = (wc & 1) * 4;    // fragment group within B-half

    for (int tau = 0; tau < 64; ++tau) {
        const char* aptr = smem + ((size_t)(tau & 1) << 16) + ((size_t)wr << 14) + lane * 16;
        const char* bptr = smem + ((size_t)(tau & 1) << 16) + 32768 + ((size_t)(wc >> 1) << 14)
                         + bsel * 1024 + lane * 16;
        const int g = tau * 4;

        // ---- phase 0: read A frags 0..3 + B frags 0..1; stage A0(t+1); MFMA (0,0)
#pragma unroll
        for (int mm = 0; mm < 4; ++mm)
#pragma unroll
            for (int ks = 0; ks < 2; ++ks)
                afr[mm][ks] = *(const bf16x8*)(aptr + (ks * 8 + mm) * 1024);
#pragma unroll
        for (int nn = 0; nn < 2; ++nn)
#pragma unroll
            for (int ks = 0; ks < 2; ++ks)
                b0[nn][ks] = *(const bf16x8*)(bptr + (ks * 8 + nn) * 1024);
        if (g + 4 < 256) stage_half(A, B, smem, g + 4, tm, tn, tid);
        MFMA_QUAD(0, 0, afr, b0)
        __builtin_amdgcn_s_barrier();

        // ---- phase 1: read B frags 2..3; stage A1(t+1); MFMA (0,1)
#pragma unroll
        for (int nn = 0; nn < 2; ++nn)
#pragma unroll
            for (int ks = 0; ks < 2; ++ks)
                b1[nn][ks] = *(const bf16x8*)(bptr + (ks * 8 + 2 + nn) * 1024);
        if (g + 5 < 256) stage_half(A, B, smem, g + 5, tm, tn, tid);
        MFMA_QUAD(0, 2, afr, b1)
        __builtin_amdgcn_s_barrier();

        // ---- phase 2: read A frags 4..7; stage B0(t+2); MFMA (1,1)
#pragma unroll
        for (int mm = 0; mm < 4; ++mm)
#pragma unroll
            for (int ks = 0; ks < 2; ++ks)
                afr[mm][ks] = *(const bf16x8*)(aptr + (ks * 8 + 4 + mm) * 1024);
        if (g + 10 < 256) stage_half(A, B, smem, g + 10, tm, tn, tid);
        MFMA_QUAD(4, 2, afr, b1)
        __builtin_amdgcn_s_barrier();

        // ---- phase 3: stage B1(t+2); MFMA (1,0); gate ALL of tile t+1
        if (g + 11 < 256) stage_half(A, B, smem, g + 11, tm, tn, tid);
        MFMA_QUAD(4, 0, afr, b0)
        if (tau < 62) {
            asm volatile("s_waitcnt vmcnt(4)" ::: "memory");
        } else {
            asm volatile("s_waitcnt vmcnt(0)" ::: "memory");
        }
        __builtin_amdgcn_s_barrier();
    }

    // epilogue: C/D layout col = lane&15, row = khi*4 + j
    const size_t crow = (size_t)(tm * 256 + wr * 128 + khi * 4);
    const int    ccol = tn * 256 + wc * 64 + fr;
#pragma unroll
    for (int m = 0; m < 8; ++m)
#pragma unroll
        for (int n = 0; n < 4; ++n) {
            float* cp = C + (crow + m * 16) * N_OUT + (ccol + n * 16);
#pragma unroll
            for (int j = 0; j < 4; ++j)
                cp[(size_t)j * N_OUT] = acc[m][n][j];
        }
}

// ---------------- fallback fp32 GEMM (only if ws too small) ----------------
__global__ __launch_bounds__(256) void fb_gemm(const float* __restrict__ X,
                                               const float* __restrict__ W,
                                               const double* __restrict__ sum,
                                               float* __restrict__ C) {
    __shared__ float Xs[64][33];
    __shared__ float Ws[64][33];
    const float gamma = (float)(*sum / NW);
    const float denom = gamma + 1e-8f;
    const int tid = threadIdx.x;
    const int bm = blockIdx.y * 64;
    const int bn = blockIdx.x * 64;
    const int tr = tid >> 4, tc = tid & 15;
    const int lrow = tid >> 2;
    const int lcol = (tid & 3) * 8;
    float acc[4][4] = {};
    for (int k0 = 0; k0 < K_DIM; k0 += 32) {
        const float4* xs = (const float4*)(X + (size_t)(bm + lrow) * K_DIM + k0 + lcol);
        float4 v0 = xs[0], v1 = xs[1];
        Xs[lrow][lcol + 0] = v0.x; Xs[lrow][lcol + 1] = v0.y;
        Xs[lrow][lcol + 2] = v0.z; Xs[lrow][lcol + 3] = v0.w;
        Xs[lrow][lcol + 4] = v1.x; Xs[lrow][lcol + 5] = v1.y;
        Xs[lrow][lcol + 6] = v1.z; Xs[lrow][lcol + 7] = v1.w;
        const float4* wsrc = (const float4*)(W + (size_t)(bn + lrow) * K_DIM + k0 + lcol);
        float4 w0 = wsrc[0], w1 = wsrc[1];
        Ws[lrow][lcol + 0] = fminf(1.f, fmaxf(-1.f, rintf(w0.x / denom)));
        Ws[lrow][lcol + 1] = fminf(1.f, fmaxf(-1.f, rintf(w0.y / denom)));
        Ws[lrow][lcol + 2] = fminf(1.f, fmaxf(-1.f, rintf(w0.z / denom)));
        Ws[lrow][lcol + 3] = fminf(1.f, fmaxf(-1.f, rintf(w0.w / denom)));
        Ws[lrow][lcol + 4] = fminf(1.f, fmaxf(-1.f, rintf(w1.x / denom)));
        Ws[lrow][lcol + 5] = fminf(1.f, fmaxf(-1.f, rintf(w1.y / denom)));
        Ws[lrow][lcol + 6] = fminf(1.f, fmaxf(-1.f, rintf(w1.z / denom)));
        Ws[lrow][lcol + 7] = fminf(1.f, fmaxf(-1.f, rintf(w1.w / denom)));
        __syncthreads();
#pragma unroll 8
        for (int kk = 0; kk < 32; ++kk) {
            float a0 = Xs[tr * 4 + 0][kk], a1 = Xs[tr * 4 + 1][kk];
            float a2 = Xs[tr * 4 + 2][kk], a3 = Xs[tr * 4 + 3][kk];
            float b0 = Ws[tc * 4 + 0][kk], b1 = Ws[tc * 4 + 1][kk];
            float b2 = Ws[tc * 4 + 2][kk], b3 = Ws[tc * 4 + 3][kk];
            acc[0][0] += a0 * b0; acc[0][1] += a0 * b1; acc[0][2] += a0 * b2; acc[0][3] += a0 * b3;
            acc[1][0] += a1 * b0; acc[1][1] += a1 * b1; acc[1][2] += a1 * b2; acc[1][3] += a1 * b3;
            acc[2][0] += a2 * b0; acc[2][1] += a2 * b1; acc[2][2] += a2 * b2; acc[2][3] += a2 * b3;
            acc[3][0] += a3 * b0; acc[3][1] += a3 * b1; acc[3][2] += a3 * b2; acc[3][3] += a3 * b3;
        }
        __syncthreads();
    }
#pragma unroll
    for (int i = 0; i < 4; ++i)
#pragma unroll
        for (int j = 0; j < 4; ++j)
            C[(size_t)(bm + tr * 4 + i) * N_OUT + (bn + tc * 4 + j)] = acc[i][j];
}

extern "C" void kernel_launch(void* const* d_in, const int* in_sizes, int n_in,
                              void* d_out, int out_size, void* d_ws, size_t ws_size,
                              hipStream_t stream) {
    (void)in_sizes; (void)n_in; (void)out_size;
    const float* x = (const float*)d_in[0];
    const float* w = (const float*)d_in[1];
    float* out = (float*)d_out;
    float* scalars = out + (size_t)M_ROWS * N_OUT;   // [t_current, entropy]

    double* sum = (double*)d_ws;
    unsigned int* counts = (unsigned int*)((char*)d_ws + 8);
    unsigned short* xb = (unsigned short*)((char*)d_ws + 64);
    unsigned short* wq = (unsigned short*)((char*)d_ws + 64 + (size_t)M_ROWS * K_DIM * 2);

    const size_t need = 64 + (size_t)M_ROWS * K_DIM * 2 + (size_t)N_OUT * K_DIM * 2;
    const int fast = (ws_size >= need);

    hipMemsetAsync(d_ws, 0, 16, stream);
    k_gamma<<<1024, 256, 0, stream>>>(w, sum);

    if (fast) {
        k_cvt<<<2048, 256, 0, stream>>>(x, xb);
        k_quant<<<1024, 256, 0, stream>>>(w, sum, wq, counts, 1);
        k_fin<<<1, 1, 0, stream>>>(counts, scalars);
        hipFuncSetAttribute(reinterpret_cast<const void*>(k_gemm2),
                            hipFuncAttributeMaxDynamicSharedMemorySize, 131072);
        k_gemm2<<<dim3(512), 512, 131072, stream>>>(xb, wq, out);
    } else {
        k_quant<<<1024, 256, 0, stream>>>(w, sum, nullptr, counts, 0);
        k_fin<<<1, 1, 0, stream>>>(counts, scalars);
        dim3 grid(N_OUT / 64, M_ROWS / 64);
        fb_gemm<<<grid, 256, 0, stream>>>(x, w, sum, out);
    }
}